// Round 1
// baseline (520.184 us; speedup 1.0000x reference)
//
#include <hip/hip_runtime.h>

typedef __bf16 bf16;
typedef __bf16 bf16x8 __attribute__((ext_vector_type(8)));
typedef __bf16 bf16x4 __attribute__((ext_vector_type(4)));
typedef float  f32x4  __attribute__((ext_vector_type(4)));

#define SCALE 0.17677669529663687f   // 32^-0.5

// workspace byte offsets
#define PQKV_OFF 0         // 110592 bf16 = 221184 B : packed Wq|Wk|Wv  [36 nt][6 kb][64 lane][8]
#define PWO_OFF  221184    //  36864 bf16 =  73728 B : packed Wo        [12 nt][6 kb][64 lane][8]
#define BQKV_OFF 294912    //    576 f32  =   2304 B : bq|bk|bv
#define BO_OFF   297216    //    192 f32  =    768 B : bo

__global__ __launch_bounds__(256)
void prep_kernel(const float* __restrict__ Wq, const float* __restrict__ bq,
                 const float* __restrict__ Wk, const float* __restrict__ bk,
                 const float* __restrict__ Wv, const float* __restrict__ bv,
                 const float* __restrict__ Wo, const float* __restrict__ bo,
                 bf16* __restrict__ pqkv, bf16* __restrict__ pwo,
                 float* __restrict__ bqkv, float* __restrict__ boc)
{
    int idx = blockIdx.x * 256 + threadIdx.x;
    if (idx < 110592) {
        int j = idx & 7, lane = (idx >> 3) & 63, kb = (idx >> 9) % 6, nt = idx / 3072;
        int n = nt * 16 + (lane & 15);
        int k = kb * 32 + ((lane >> 4) << 3) + j;
        float v;
        if (n < 192)      v = Wq[k * 192 + n];
        else if (n < 384) v = Wk[k * 192 + (n - 192)];
        else              v = Wv[k * 192 + (n - 384)];
        pqkv[idx] = (bf16)v;
    } else if (idx < 110592 + 36864) {
        int p = idx - 110592;
        int j = p & 7, lane = (p >> 3) & 63, kb = (p >> 9) % 6, nt = p / 3072;
        int n = nt * 16 + (lane & 15);
        int k = kb * 32 + ((lane >> 4) << 3) + j;
        pwo[p] = (bf16)Wo[k * 192 + n];
    } else if (idx < 110592 + 36864 + 576) {
        int p = idx - 110592 - 36864;
        float v = (p < 192) ? bq[p] : (p < 384) ? bk[p - 192] : bv[p - 384];
        bqkv[p] = v;
    } else if (idx < 110592 + 36864 + 576 + 192) {
        int p = idx - 110592 - 36864 - 576;
        boc[p] = bo[p];
    }
}

// LDS layout (bf16 elements), dynamic:
//   xo : [64][200]  x window (bf16), later reused as attention output o
//   q  : [64][200]
//   kk : [64][200]
//   vT : [192][72]  v transposed (channel-major) so PV B-frags are contiguous
//   pl : [8 waves][16][72]  per-wave P round-trip buffer
// strides 200 and 72 give row bank-stride 4 (mod 32) -> only free 2-way conflicts,
// and both are multiples of 8 elems so all b128 reads stay 16B-aligned.
//
// 8-wave (512-thread) version: 2 waves/SIMD (was 1) to hide ds_read/L2/softmax
// latency; per-wave serial chains halved. LDS = 122880 B -> still 1 block/CU.

__global__ __launch_bounds__(512, 1)
void winattn_kernel(const float* __restrict__ x,
                    const bf16* __restrict__ pqkv, const bf16* __restrict__ pwo,
                    const float* __restrict__ bqkv, const float* __restrict__ boc,
                    float* __restrict__ out)
{
    extern __shared__ char smem_raw[];
    bf16* xo = (bf16*)smem_raw;          // 64*200
    bf16* q  = xo + 64 * 200;
    bf16* kk = q  + 64 * 200;
    bf16* vT = kk + 64 * 200;            // 192*72
    bf16* pl = vT + 192 * 72;            // 8*16*72

    const int tid  = threadIdx.x;
    const int w    = tid >> 6;           // 0..7
    const int lane = tid & 63;
    const int quad = lane >> 4;
    const int ln   = lane & 15;

    const int blk = blockIdx.x;
    const int b   = blk >> 6;
    const int rem = blk & 63;
    const int h0  = (rem >> 3) * 7;
    const int w0  = (rem & 7) * 7;
    const float* xbase = x   + ((size_t)(b * 56 + h0) * 56 + w0) * 192;
    float*       obase = out + ((size_t)(b * 56 + h0) * 56 + w0) * 192;

    // ---- phase 1: stage x window -> LDS bf16, zero pad rows 49..63 ----
    for (int i = tid; i < 64 * 48; i += 512) {
        int row = i / 48;
        int c4  = (i % 48) * 4;
        f32x4 v = {0.f, 0.f, 0.f, 0.f};
        if (row < 49) {
            const float* p = xbase + ((row / 7) * 56 + (row % 7)) * 192 + c4;
            v = *(const f32x4*)p;
        }
        bf16x4 hv;
        hv[0] = (bf16)v[0]; hv[1] = (bf16)v[1]; hv[2] = (bf16)v[2]; hv[3] = (bf16)v[3];
        *(bf16x4*)&xo[row * 200 + c4] = hv;
    }
    __syncthreads();

    // ---- phase 2: QKV GEMM  C[64 x 576] = x @ Wqkv + b ----
    // wave w: row-tiles mt0..mt0+1 (mt0 = (w>>2)*2), col-tiles nt = (w&3)+4i
    {
        const int mt0 = (w >> 2) * 2;
        const int cw  = w & 3;
        f32x4 acc[2][9];
        #pragma unroll
        for (int mt = 0; mt < 2; mt++)
            #pragma unroll
            for (int i = 0; i < 9; i++) acc[mt][i] = (f32x4){0.f, 0.f, 0.f, 0.f};

        #pragma unroll
        for (int kb = 0; kb < 6; kb++) {
            bf16x8 A[2];
            #pragma unroll
            for (int mt = 0; mt < 2; mt++)
                A[mt] = *(const bf16x8*)&xo[((mt0 + mt) * 16 + ln) * 200 + kb * 32 + quad * 8];
            #pragma unroll
            for (int i = 0; i < 9; i++) {
                int nt = cw + 4 * i;
                bf16x8 B = *(const bf16x8*)&pqkv[((nt * 6 + kb) * 64 + lane) * 8];
                #pragma unroll
                for (int mt = 0; mt < 2; mt++)
                    acc[mt][i] = __builtin_amdgcn_mfma_f32_16x16x32_bf16(A[mt], B, acc[mt][i], 0, 0, 0);
            }
        }
        // bias + store to q / k / vT (branch is wave-uniform: nt ≡ w&3 mod 4, splits at 12/24)
        #pragma unroll
        for (int i = 0; i < 9; i++) {
            int nt = cw + 4 * i;
            int n  = nt * 16 + ln;
            float bias = bqkv[n];
            if (n < 192) {
                #pragma unroll
                for (int mt = 0; mt < 2; mt++)
                    #pragma unroll
                    for (int r = 0; r < 4; r++)
                        q[((mt0 + mt) * 16 + quad * 4 + r) * 200 + n] = (bf16)(acc[mt][i][r] + bias);
            } else if (n < 384) {
                #pragma unroll
                for (int mt = 0; mt < 2; mt++)
                    #pragma unroll
                    for (int r = 0; r < 4; r++)
                        kk[((mt0 + mt) * 16 + quad * 4 + r) * 200 + (n - 192)] = (bf16)(acc[mt][i][r] + bias);
            } else {
                #pragma unroll
                for (int mt = 0; mt < 2; mt++) {
                    bf16x4 hv;
                    #pragma unroll
                    for (int r = 0; r < 4; r++) hv[r] = (bf16)(acc[mt][i][r] + bias);
                    *(bf16x4*)&vT[(n - 384) * 72 + (mt0 + mt) * 16 + quad * 4] = hv;
                }
            }
        }
    }
    __syncthreads();

    // ---- phase 3: attention. wave w owns query rows [16*rt, 16*rt+16), heads h ≡ (w&1) mod 2 ----
    {
        const int rt = w >> 1;
        const int hg = w & 1;
        bf16* pw = pl + w * (16 * 72);
        #pragma unroll 1
        for (int h = hg; h < 6; h += 2) {
            // S = q @ k^T  (K = HD = 32, single MFMA step; 4 key tiles)
            bf16x8 aq = *(const bf16x8*)&q[(rt * 16 + ln) * 200 + h * 32 + quad * 8];
            f32x4 s[4];
            #pragma unroll
            for (int nt = 0; nt < 4; nt++) {
                bf16x8 bk8 = *(const bf16x8*)&kk[(nt * 16 + ln) * 200 + h * 32 + quad * 8];
                s[nt] = __builtin_amdgcn_mfma_f32_16x16x32_bf16(aq, bk8, (f32x4){0.f, 0.f, 0.f, 0.f}, 0, 0, 0);
            }
            // scale + mask cols >= 49, row max/sum via shfl over the 16-lane group
            float rmax[4] = {-1e30f, -1e30f, -1e30f, -1e30f};
            #pragma unroll
            for (int nt = 0; nt < 4; nt++) {
                int col = nt * 16 + ln;
                #pragma unroll
                for (int r = 0; r < 4; r++) {
                    float v = s[nt][r] * SCALE;
                    v = (col < 49) ? v : -1e30f;
                    s[nt][r] = v;
                    rmax[r] = fmaxf(rmax[r], v);
                }
            }
            #pragma unroll
            for (int xm = 1; xm < 16; xm <<= 1)
                #pragma unroll
                for (int r = 0; r < 4; r++)
                    rmax[r] = fmaxf(rmax[r], __shfl_xor(rmax[r], xm, 64));
            float rsum[4] = {0.f, 0.f, 0.f, 0.f};
            #pragma unroll
            for (int nt = 0; nt < 4; nt++)
                #pragma unroll
                for (int r = 0; r < 4; r++) {
                    float p = __expf(s[nt][r] - rmax[r]);
                    s[nt][r] = p;
                    rsum[r] += p;
                }
            #pragma unroll
            for (int xm = 1; xm < 16; xm <<= 1)
                #pragma unroll
                for (int r = 0; r < 4; r++)
                    rsum[r] += __shfl_xor(rsum[r], xm, 64);
            // P -> per-wave LDS (C-layout write, A-layout read; same-wave DS ordering)
            #pragma unroll
            for (int nt = 0; nt < 4; nt++)
                #pragma unroll
                for (int r = 0; r < 4; r++)
                    pw[(quad * 4 + r) * 72 + nt * 16 + ln] = (bf16)s[nt][r];

            float rinv[4];
            #pragma unroll
            for (int r = 0; r < 4; r++) rinv[r] = 1.0f / rsum[r];

            bf16x8 ap0 = *(const bf16x8*)&pw[ln * 72 + quad * 8];
            bf16x8 ap1 = *(const bf16x8*)&pw[ln * 72 + 32 + quad * 8];
            #pragma unroll
            for (int nt2 = 0; nt2 < 2; nt2++) {
                f32x4 o = {0.f, 0.f, 0.f, 0.f};
                bf16x8 bv0 = *(const bf16x8*)&vT[(h * 32 + nt2 * 16 + ln) * 72 + quad * 8];
                bf16x8 bv1 = *(const bf16x8*)&vT[(h * 32 + nt2 * 16 + ln) * 72 + 32 + quad * 8];
                o = __builtin_amdgcn_mfma_f32_16x16x32_bf16(ap0, bv0, o, 0, 0, 0);
                o = __builtin_amdgcn_mfma_f32_16x16x32_bf16(ap1, bv1, o, 0, 0, 0);
                #pragma unroll
                for (int r = 0; r < 4; r++)
                    xo[(rt * 16 + quad * 4 + r) * 200 + h * 32 + nt2 * 16 + ln] = (bf16)(o[r] * rinv[r]);
            }
        }
    }
    __syncthreads();

    // ---- phase 4: output projection  out = o @ Wo + bo ----
    // wave w: row-tiles mt0..mt0+1, col-tiles nt = (w&3)*3 + i
    {
        const int mt0 = (w >> 2) * 2;
        const int ntb = (w & 3) * 3;
        f32x4 acc[2][3];
        #pragma unroll
        for (int mt = 0; mt < 2; mt++)
            #pragma unroll
            for (int i = 0; i < 3; i++) acc[mt][i] = (f32x4){0.f, 0.f, 0.f, 0.f};

        #pragma unroll
        for (int kb = 0; kb < 6; kb++) {
            bf16x8 A[2];
            #pragma unroll
            for (int mt = 0; mt < 2; mt++)
                A[mt] = *(const bf16x8*)&xo[((mt0 + mt) * 16 + ln) * 200 + kb * 32 + quad * 8];
            #pragma unroll
            for (int i = 0; i < 3; i++) {
                int nt = ntb + i;
                bf16x8 B = *(const bf16x8*)&pwo[((nt * 6 + kb) * 64 + lane) * 8];
                #pragma unroll
                for (int mt = 0; mt < 2; mt++)
                    acc[mt][i] = __builtin_amdgcn_mfma_f32_16x16x32_bf16(A[mt], B, acc[mt][i], 0, 0, 0);
            }
        }
        #pragma unroll
        for (int i = 0; i < 3; i++) {
            int nt = ntb + i;
            int n  = nt * 16 + ln;
            float bias = boc[n];
            #pragma unroll
            for (int mt = 0; mt < 2; mt++)
                #pragma unroll
                for (int r = 0; r < 4; r++) {
                    int l = (mt0 + mt) * 16 + quad * 4 + r;
                    if (l < 49)
                        obase[((l / 7) * 56 + (l % 7)) * 192 + n] = acc[mt][i][r] + bias;
                }
        }
    }
}

extern "C" void kernel_launch(void* const* d_in, const int* in_sizes, int n_in,
                              void* d_out, int out_size, void* d_ws, size_t ws_size,
                              hipStream_t stream)
{
    const float* x  = (const float*)d_in[0];
    const float* Wq = (const float*)d_in[1];
    const float* bq = (const float*)d_in[2];
    const float* Wk = (const float*)d_in[3];
    const float* bk = (const float*)d_in[4];
    const float* Wv = (const float*)d_in[5];
    const float* bv = (const float*)d_in[6];
    const float* Wo = (const float*)d_in[7];
    const float* bo = (const float*)d_in[8];
    float* out = (float*)d_out;

    bf16*  pqkv = (bf16*)((char*)d_ws + PQKV_OFF);
    bf16*  pwo  = (bf16*)((char*)d_ws + PWO_OFF);
    float* bqkv = (float*)((char*)d_ws + BQKV_OFF);
    float* boc  = (float*)((char*)d_ws + BO_OFF);

    // repack weights (d_ws is re-poisoned before every launch, so always rerun)
    prep_kernel<<<579, 256, 0, stream>>>(Wq, bq, Wk, bk, Wv, bv, Wo, bo,
                                         pqkv, pwo, bqkv, boc);

    const size_t smem = (size_t)(64 * 200 * 3 + 192 * 72 + 8 * 16 * 72) * sizeof(bf16); // 122880 B
    winattn_kernel<<<4096, 512, smem, stream>>>(x, pqkv, pwo, bqkv, boc, out);
}

// Round 2
// 456.285 us; speedup vs baseline: 1.1400x; 1.1400x over previous
//
#include <hip/hip_runtime.h>

typedef __bf16 bf16;
typedef __bf16 bf16x8 __attribute__((ext_vector_type(8)));
typedef __bf16 bf16x4 __attribute__((ext_vector_type(4)));
typedef float  f32x4  __attribute__((ext_vector_type(4)));

#define SCALE 0.17677669529663687f   // 32^-0.5

// workspace byte offsets
#define PQKV_OFF 0         // 110592 bf16 = 221184 B : packed Wq|Wk|Wv  [36 nt][6 kb][64 lane][8]
#define PWO_OFF  221184    //  36864 bf16 =  73728 B : packed Wo        [12 nt][6 kb][64 lane][8]
#define BQKV_OFF 294912    //    576 f32  =   2304 B : bq|bk|bv
#define BO_OFF   297216    //    192 f32  =    768 B : bo

__global__ __launch_bounds__(256)
void prep_kernel(const float* __restrict__ Wq, const float* __restrict__ bq,
                 const float* __restrict__ Wk, const float* __restrict__ bk,
                 const float* __restrict__ Wv, const float* __restrict__ bv,
                 const float* __restrict__ Wo, const float* __restrict__ bo,
                 bf16* __restrict__ pqkv, bf16* __restrict__ pwo,
                 float* __restrict__ bqkv, float* __restrict__ boc)
{
    int idx = blockIdx.x * 256 + threadIdx.x;
    if (idx < 110592) {
        int j = idx & 7, lane = (idx >> 3) & 63, kb = (idx >> 9) % 6, nt = idx / 3072;
        int n = nt * 16 + (lane & 15);
        int k = kb * 32 + ((lane >> 4) << 3) + j;
        float v;
        if (n < 192)      v = Wq[k * 192 + n];
        else if (n < 384) v = Wk[k * 192 + (n - 192)];
        else              v = Wv[k * 192 + (n - 384)];
        pqkv[idx] = (bf16)v;
    } else if (idx < 110592 + 36864) {
        int p = idx - 110592;
        int j = p & 7, lane = (p >> 3) & 63, kb = (p >> 9) % 6, nt = p / 3072;
        int n = nt * 16 + (lane & 15);
        int k = kb * 32 + ((lane >> 4) << 3) + j;
        pwo[p] = (bf16)Wo[k * 192 + n];
    } else if (idx < 110592 + 36864 + 576) {
        int p = idx - 110592 - 36864;
        float v = (p < 192) ? bq[p] : (p < 384) ? bk[p - 192] : bv[p - 384];
        bqkv[p] = v;
    } else if (idx < 110592 + 36864 + 576 + 192) {
        int p = idx - 110592 - 36864 - 576;
        boc[p] = bo[p];
    }
}

__device__ inline unsigned pack2(float a, float b)
{
    union { bf16 h[2]; unsigned u; } t;
    t.h[0] = (bf16)a; t.h[1] = (bf16)b;
    return t.u;
}

// LDS layout (bf16 elements), dynamic — 78848 B total -> 2 blocks/CU:
//   q  : [64][200]  Q (row-major); phase-3 writes attention output o into the
//                   same head-columns each wave reads (parity-disjoint, safe)
//   kk : [64][200]  K row-major
//   vT : [192][72]  V transposed (channel-major) so PV B-frags are contiguous
// strides 200 and 72 give row bank-stride 4 (mod 32) -> only free 2-way
// conflicts; multiples of 8 elems keep all b128 reads 16B-aligned.
// Rows/keys 49..63 of q/kk/vT hold bias values (finite) -> masked or discarded.

__global__ __launch_bounds__(512, 4)
void winattn_kernel(const float* __restrict__ x,
                    const bf16* __restrict__ pqkv, const bf16* __restrict__ pwo,
                    const float* __restrict__ bqkv, const float* __restrict__ boc,
                    float* __restrict__ out)
{
    extern __shared__ char smem_raw[];
    bf16* q  = (bf16*)smem_raw;          // 64*200
    bf16* kk = q  + 64 * 200;
    bf16* vT = kk + 64 * 200;            // 192*72

    const int tid  = threadIdx.x;
    const int w    = tid >> 6;           // 0..7
    const int lane = tid & 63;
    const int quad = lane >> 4;
    const int ln   = lane & 15;

    const int blk = blockIdx.x;
    const int b   = blk >> 6;
    const int rem = blk & 63;
    const int h0  = (rem >> 3) * 7;
    const int w0  = (rem & 7) * 7;
    const float* xbase = x   + ((size_t)(b * 56 + h0) * 56 + w0) * 192;
    float*       obase = out + ((size_t)(b * 56 + h0) * 56 + w0) * 192;

    // ---- phase 2: QKV GEMM  C[64 x 576] = x @ Wqkv + b ----
    // wave w: row-tiles mt0..mt0+1 (mt0=(w>>2)*2), col-tiles nt = (w&3)+4i.
    // A-frags come straight from global x (predicated pad rows -> 0).
    {
        const int mt0 = (w >> 2) * 2;
        const int cw  = w & 3;

        bf16x8 Afr[2][6];
        #pragma unroll
        for (int mt = 0; mt < 2; mt++) {
            int wr = (mt0 + mt) * 16 + ln;
            bool valid = wr < 49;
            int wrc = valid ? wr : 0;
            const float* rp_ = xbase + ((wrc / 7) * 56 + (wrc % 7)) * 192;
            #pragma unroll
            for (int kb = 0; kb < 6; kb++) {
                f32x4 a0 = *(const f32x4*)(rp_ + kb * 32 + quad * 8);
                f32x4 a1 = *(const f32x4*)(rp_ + kb * 32 + quad * 8 + 4);
                if (!valid) { a0 = (f32x4){0.f,0.f,0.f,0.f}; a1 = (f32x4){0.f,0.f,0.f,0.f}; }
                bf16x8 fr;
                #pragma unroll
                for (int j = 0; j < 4; j++) { fr[j] = (bf16)a0[j]; fr[4 + j] = (bf16)a1[j]; }
                Afr[mt][kb] = fr;
            }
        }

        #pragma unroll 1
        for (int c = 0; c < 3; c++) {
            f32x4 acc[2][3];
            #pragma unroll
            for (int mt = 0; mt < 2; mt++)
                #pragma unroll
                for (int i = 0; i < 3; i++) acc[mt][i] = (f32x4){0.f,0.f,0.f,0.f};

            #pragma unroll
            for (int i = 0; i < 3; i++) {
                int nt = cw + 4 * (c * 3 + i);
                #pragma unroll
                for (int kb = 0; kb < 6; kb++) {
                    bf16x8 B = *(const bf16x8*)&pqkv[((nt * 6 + kb) * 64 + lane) * 8];
                    acc[0][i] = __builtin_amdgcn_mfma_f32_16x16x32_bf16(Afr[0][kb], B, acc[0][i], 0, 0, 0);
                    acc[1][i] = __builtin_amdgcn_mfma_f32_16x16x32_bf16(Afr[1][kb], B, acc[1][i], 0, 0, 0);
                }
            }
            // bias + store to q / kk / vT (branch wave-uniform per i)
            #pragma unroll
            for (int i = 0; i < 3; i++) {
                int nt = cw + 4 * (c * 3 + i);
                int n  = nt * 16 + ln;
                float bias = bqkv[n];
                if (n < 192) {
                    #pragma unroll
                    for (int mt = 0; mt < 2; mt++)
                        #pragma unroll
                        for (int r = 0; r < 4; r++)
                            q[((mt0 + mt) * 16 + quad * 4 + r) * 200 + n] = (bf16)(acc[mt][i][r] + bias);
                } else if (n < 384) {
                    #pragma unroll
                    for (int mt = 0; mt < 2; mt++)
                        #pragma unroll
                        for (int r = 0; r < 4; r++)
                            kk[((mt0 + mt) * 16 + quad * 4 + r) * 200 + (n - 192)] = (bf16)(acc[mt][i][r] + bias);
                } else {
                    #pragma unroll
                    for (int mt = 0; mt < 2; mt++) {
                        bf16x4 hv;
                        #pragma unroll
                        for (int r = 0; r < 4; r++) hv[r] = (bf16)(acc[mt][i][r] + bias);
                        *(bf16x4*)&vT[(n - 384) * 72 + (mt0 + mt) * 16 + quad * 4] = hv;
                    }
                }
            }
        }
    }
    __syncthreads();

    // ---- phase 3: attention (swapped QK^T, in-register P transpose) ----
    // wave w owns query rows [16*rt,16*rt+16), heads h ≡ (w&1) (mod 2).
    {
        const int rt = w >> 1;
        const int hg = w & 1;
        // bpermute byte indices: src lane = (2*(quad&1) + (w2>>1))*16 + ln
        const int idxA = (((lane & 16) >> 4) * 32 + ln) * 4;   // w2 in {0,1}
        const int idxB = idxA + 64;                            // w2 in {2,3}

        #pragma unroll 1
        for (int h = hg; h < 6; h += 2) {
            // S^T = K @ Q^T : lane holds P[key = nt*16+quad*4+r][qrow = ln]
            bf16x8 bq8 = *(const bf16x8*)&q[(rt * 16 + ln) * 200 + h * 32 + quad * 8];
            f32x4 s[4];
            #pragma unroll
            for (int nt = 0; nt < 4; nt++) {
                bf16x8 ak = *(const bf16x8*)&kk[(nt * 16 + ln) * 200 + h * 32 + quad * 8];
                s[nt] = __builtin_amdgcn_mfma_f32_16x16x32_bf16(ak, bq8, (f32x4){0.f,0.f,0.f,0.f}, 0, 0, 0);
            }
            // scale + mask keys >= 49; row-reduce over key (the lane-high bits)
            float m = -1e30f;
            #pragma unroll
            for (int nt = 0; nt < 4; nt++)
                #pragma unroll
                for (int r = 0; r < 4; r++) {
                    float v = s[nt][r] * SCALE;
                    v = (nt * 16 + quad * 4 + r < 49) ? v : -1e30f;
                    s[nt][r] = v;
                    m = fmaxf(m, v);
                }
            m = fmaxf(m, __shfl_xor(m, 16, 64));
            m = fmaxf(m, __shfl_xor(m, 32, 64));
            float sum = 0.f;
            #pragma unroll
            for (int nt = 0; nt < 4; nt++)
                #pragma unroll
                for (int r = 0; r < 4; r++) {
                    float p = __expf(s[nt][r] - m);
                    s[nt][r] = p;
                    sum += p;
                }
            sum += __shfl_xor(sum, 16, 64);
            sum += __shfl_xor(sum, 32, 64);
            float rinv = 1.0f / sum;
            #pragma unroll
            for (int nt = 0; nt < 4; nt++)
                #pragma unroll
                for (int r = 0; r < 4; r++) s[nt][r] *= rinv;

            // pack pairs: pk[nt][rp] = keys (nt*16+quad*4+2rp, +1) at qrow=ln
            unsigned pk[4][2];
            #pragma unroll
            for (int nt = 0; nt < 4; nt++) {
                pk[nt][0] = pack2(s[nt][0], s[nt][1]);
                pk[nt][1] = pack2(s[nt][2], s[nt][3]);
            }
            // in-register transpose -> PV A-frags:
            // ap[ntA] word w2 = keys (ntA*32 + quad*8 + 2*w2, +1), qrow = ln
            //   src value pk[2*ntA + (quad>>1)][w2&1], src lane (2*(quad&1)+(w2>>1))*16+ln
            union { unsigned u[4]; bf16x8 v; } ap[2];
            #pragma unroll
            for (int ntA = 0; ntA < 2; ntA++)
                #pragma unroll
                for (int w2 = 0; w2 < 4; w2++) {
                    int idx = (w2 < 2) ? idxA : idxB;
                    unsigned lo = __builtin_amdgcn_ds_bpermute(idx, (int)pk[2 * ntA][w2 & 1]);
                    unsigned hi = __builtin_amdgcn_ds_bpermute(idx, (int)pk[2 * ntA + 1][w2 & 1]);
                    ap[ntA].u[w2] = (quad & 2) ? hi : lo;
                }

            // O = P @ V ; write o into q's head-h columns (parity-disjoint)
            #pragma unroll
            for (int nt2 = 0; nt2 < 2; nt2++) {
                f32x4 o = {0.f, 0.f, 0.f, 0.f};
                bf16x8 bv0 = *(const bf16x8*)&vT[(h * 32 + nt2 * 16 + ln) * 72 + quad * 8];
                bf16x8 bv1 = *(const bf16x8*)&vT[(h * 32 + nt2 * 16 + ln) * 72 + 32 + quad * 8];
                o = __builtin_amdgcn_mfma_f32_16x16x32_bf16(ap[0].v, bv0, o, 0, 0, 0);
                o = __builtin_amdgcn_mfma_f32_16x16x32_bf16(ap[1].v, bv1, o, 0, 0, 0);
                #pragma unroll
                for (int r = 0; r < 4; r++)
                    q[(rt * 16 + quad * 4 + r) * 200 + h * 32 + nt2 * 16 + ln] = (bf16)o[r];
            }
        }
    }
    __syncthreads();

    // ---- phase 4: output projection  out = o @ Wo + bo  (o lives in q) ----
    {
        const int mt0  = (w >> 2) * 2;
        const int ntb4 = (w & 3) * 3;
        f32x4 acc[2][3];
        #pragma unroll
        for (int mt = 0; mt < 2; mt++)
            #pragma unroll
            for (int i = 0; i < 3; i++) acc[mt][i] = (f32x4){0.f,0.f,0.f,0.f};

        #pragma unroll
        for (int kb = 0; kb < 6; kb++) {
            bf16x8 A[2];
            #pragma unroll
            for (int mt = 0; mt < 2; mt++)
                A[mt] = *(const bf16x8*)&q[((mt0 + mt) * 16 + ln) * 200 + kb * 32 + quad * 8];
            #pragma unroll
            for (int i = 0; i < 3; i++) {
                int nt = ntb4 + i;
                bf16x8 B = *(const bf16x8*)&pwo[((nt * 6 + kb) * 64 + lane) * 8];
                #pragma unroll
                for (int mt = 0; mt < 2; mt++)
                    acc[mt][i] = __builtin_amdgcn_mfma_f32_16x16x32_bf16(A[mt], B, acc[mt][i], 0, 0, 0);
            }
        }
        #pragma unroll
        for (int i = 0; i < 3; i++) {
            int nt = ntb4 + i;
            int n  = nt * 16 + ln;
            float bias = boc[n];
            #pragma unroll
            for (int mt = 0; mt < 2; mt++)
                #pragma unroll
                for (int r = 0; r < 4; r++) {
                    int l = (mt0 + mt) * 16 + quad * 4 + r;
                    if (l < 49)
                        obase[((l / 7) * 56 + (l % 7)) * 192 + n] = acc[mt][i][r] + bias;
                }
        }
    }
}

extern "C" void kernel_launch(void* const* d_in, const int* in_sizes, int n_in,
                              void* d_out, int out_size, void* d_ws, size_t ws_size,
                              hipStream_t stream)
{
    const float* x  = (const float*)d_in[0];
    const float* Wq = (const float*)d_in[1];
    const float* bq = (const float*)d_in[2];
    const float* Wk = (const float*)d_in[3];
    const float* bk = (const float*)d_in[4];
    const float* Wv = (const float*)d_in[5];
    const float* bv = (const float*)d_in[6];
    const float* Wo = (const float*)d_in[7];
    const float* bo = (const float*)d_in[8];
    float* out = (float*)d_out;

    bf16*  pqkv = (bf16*)((char*)d_ws + PQKV_OFF);
    bf16*  pwo  = (bf16*)((char*)d_ws + PWO_OFF);
    float* bqkv = (float*)((char*)d_ws + BQKV_OFF);
    float* boc  = (float*)((char*)d_ws + BO_OFF);

    // repack weights (d_ws is re-poisoned before every launch, so always rerun)
    prep_kernel<<<579, 256, 0, stream>>>(Wq, bq, Wk, bk, Wv, bv, Wo, bo,
                                         pqkv, pwo, bqkv, boc);

    const size_t smem = (size_t)(64 * 200 * 2 + 192 * 72) * sizeof(bf16); // 78848 B
    winattn_kernel<<<4096, 512, smem, stream>>>(x, pqkv, pwo, bqkv, boc, out);
}